// Round 1
// baseline (1221.956 us; speedup 1.0000x reference)
//
#include <hip/hip_runtime.h>
#include <math.h>

#define NTOK 1024
#define DMODEL 1024
#define NHEAD 8
#define HDIM 128
#define BATCH 4

// ---------------- LayerNorm (x -> normed) ----------------
__global__ __launch_bounds__(256) void ln_kernel(
    const float* __restrict__ x, const float* __restrict__ g,
    const float* __restrict__ b, float* __restrict__ out)
{
  const int row = blockIdx.x;
  const int tid = threadIdx.x;
  const float* xr = x + (size_t)row * DMODEL;
  float4 v = *(const float4*)(xr + 4 * tid);
  float s1 = v.x + v.y + v.z + v.w;
  float s2 = v.x * v.x + v.y * v.y + v.z * v.z + v.w * v.w;
#pragma unroll
  for (int d = 1; d < 64; d <<= 1) { s1 += __shfl_xor(s1, d); s2 += __shfl_xor(s2, d); }
  __shared__ float red[10];
  const int wid = tid >> 6;
  if ((tid & 63) == 0) { red[wid] = s1; red[4 + wid] = s2; }
  __syncthreads();
  if (tid == 0) {
    float a = red[0] + red[1] + red[2] + red[3];
    float c = red[4] + red[5] + red[6] + red[7];
    float mu = a / (float)DMODEL;
    float var = c / (float)DMODEL - mu * mu;
    red[8] = mu; red[9] = rsqrtf(var + 1e-5f);
  }
  __syncthreads();
  const float mu = red[8], inv = red[9];
  float4 gg = *(const float4*)(g + 4 * tid);
  float4 bb = *(const float4*)(b + 4 * tid);
  float4 o;
  o.x = (v.x - mu) * inv * gg.x + bb.x;
  o.y = (v.y - mu) * inv * gg.y + bb.y;
  o.z = (v.z - mu) * inv * gg.z + bb.z;
  o.w = (v.w - mu) * inv * gg.w + bb.w;
  *(float4*)(out + (size_t)row * DMODEL + 4 * tid) = o;
}

// ---------------- Sparse gated attention + residual + LN2 ----------------
// one block per (b, q); 256 threads; thread t owns dims [4t, 4t+4), head = t>>5
__global__ __launch_bounds__(256) void attn_kernel(
    const float* __restrict__ x, const float* __restrict__ normed,
    const int* __restrict__ adj, const float* __restrict__ stoich,
    const float* __restrict__ gW, const float* __restrict__ gb,
    const float* __restrict__ ln2g, const float* __restrict__ ln2b,
    float* __restrict__ xout, float* __restrict__ normed2)
{
  __shared__ int   neigh[NTOK];
  __shared__ float gateS[NTOK];
  __shared__ float sc[NTOK * NHEAD];  // 32 KB
  __shared__ int   cntS;
  __shared__ float red[10];

  const int bq = blockIdx.x;
  const int b = bq >> 10, q = bq & 1023;
  const int tid = threadIdx.x;

  if (tid == 0) cntS = 0;
  __syncthreads();
  const int* arow = adj + ((size_t)b * NTOK + q) * NTOK;
  for (int k = tid; k < NTOK; k += 256)
    if (arow[k] > 0) { int p = atomicAdd(&cntS, 1); neigh[p] = k; }
  __syncthreads();
  const int cnt = cntS;

  const float st = stoich[b * NTOK + q];
  for (int i = tid; i < cnt; i += 256) {
    int k = neigh[i];
    float z = fmaf(st, gW[k], gb[k]);
    gateS[i] = 1.f / (1.f + expf(-z));
  }
  __syncthreads();

  const float* nb = normed + (size_t)b * NTOK * DMODEL;
  const float4 qv = *(const float4*)(nb + (size_t)q * DMODEL + 4 * tid);
  const int head = tid >> 5, lane = tid & 31;
  const float scale = 0.08838834764831845f;  // 1/sqrt(128)

  for (int i = 0; i < cnt; ++i) {
    const float4 kv = *(const float4*)(nb + (size_t)neigh[i] * DMODEL + 4 * tid);
    float p = qv.x * kv.x + qv.y * kv.y + qv.z * kv.z + qv.w * kv.w;
    p += __shfl_xor(p, 1);  p += __shfl_xor(p, 2);  p += __shfl_xor(p, 4);
    p += __shfl_xor(p, 8);  p += __shfl_xor(p, 16);
    if (lane == 0) sc[i * NHEAD + head] = p * scale * gateS[i];
  }
  __syncthreads();

  // softmax over neighbor list, per head (32-thread group per head)
  float m = -1e30f;
  for (int i = lane; i < cnt; i += 32) m = fmaxf(m, sc[i * NHEAD + head]);
#pragma unroll
  for (int d = 1; d < 32; d <<= 1) m = fmaxf(m, __shfl_xor(m, d));
  float ssum = 0.f;
  for (int i = lane; i < cnt; i += 32) {
    float e = expf(sc[i * NHEAD + head] - m);
    sc[i * NHEAD + head] = e;
    ssum += e;
  }
#pragma unroll
  for (int d = 1; d < 32; d <<= 1) ssum += __shfl_xor(ssum, d);
  const float pinv = 1.f / ssum;
  __syncthreads();

  float4 o = make_float4(0.f, 0.f, 0.f, 0.f);
  for (int i = 0; i < cnt; ++i) {
    const float p = sc[i * NHEAD + head];
    const float4 kv = *(const float4*)(nb + (size_t)neigh[i] * DMODEL + 4 * tid);
    o.x = fmaf(p, kv.x, o.x); o.y = fmaf(p, kv.y, o.y);
    o.z = fmaf(p, kv.z, o.z); o.w = fmaf(p, kv.w, o.w);
  }

  const float4 xv = *(const float4*)(x + ((size_t)b * NTOK + q) * DMODEL + 4 * tid);
  float4 r;
  r.x = xv.x + o.x * pinv; r.y = xv.y + o.y * pinv;
  r.z = xv.z + o.z * pinv; r.w = xv.w + o.w * pinv;
  *(float4*)(xout + ((size_t)b * NTOK + q) * DMODEL + 4 * tid) = r;

  // fused LN2 on the residual row
  float s1 = r.x + r.y + r.z + r.w;
  float s2 = r.x * r.x + r.y * r.y + r.z * r.z + r.w * r.w;
#pragma unroll
  for (int d = 1; d < 64; d <<= 1) { s1 += __shfl_xor(s1, d); s2 += __shfl_xor(s2, d); }
  const int wid = tid >> 6;
  if ((tid & 63) == 0) { red[wid] = s1; red[4 + wid] = s2; }
  __syncthreads();
  if (tid == 0) {
    float a = red[0] + red[1] + red[2] + red[3];
    float c = red[4] + red[5] + red[6] + red[7];
    float mu = a / (float)DMODEL;
    float var = c / (float)DMODEL - mu * mu;
    red[8] = mu; red[9] = rsqrtf(var + 1e-5f);
  }
  __syncthreads();
  const float mu = red[8], inv = red[9];
  float4 gg = *(const float4*)(ln2g + 4 * tid);
  float4 bb = *(const float4*)(ln2b + 4 * tid);
  float4 nrm;
  nrm.x = (r.x - mu) * inv * gg.x + bb.x;
  nrm.y = (r.y - mu) * inv * gg.y + bb.y;
  nrm.z = (r.z - mu) * inv * gg.z + bb.z;
  nrm.w = (r.w - mu) * inv * gg.w + bb.w;
  *(float4*)(normed2 + ((size_t)b * NTOK + q) * DMODEL + 4 * tid) = nrm;
}

// ---------------- fp32 tiled GEMM, 64x64 tile, BK=16, 4x4 per thread ----------
// EPI==0: C = gelu(A@B + bias)         (exact erf gelu)
// EPI==1: C = res + A@B + bias
template <int EPI>
__global__ __launch_bounds__(256) void gemm64(
    const float* __restrict__ A, const float* __restrict__ B,
    const float* __restrict__ bias, const float* __restrict__ res,
    float* __restrict__ C, int M, int N, int K)
{
  __shared__ float As[16][68];
  __shared__ float Bs[16][68];
  const int bm = blockIdx.y * 64, bn = blockIdx.x * 64;
  const int tid = threadIdx.x;
  const int tx = tid & 15, ty = tid >> 4;
  const int am = tid >> 2, ac = (tid & 3) << 2;   // A tile: row am, k-offset ac
  const int br = tid >> 4, bc = (tid & 15) << 2;  // B tile: k-row br, col bc

  float acc[4][4] = {};
  const float* Aptr = A + (size_t)(bm + am) * K + ac;
  const float* Bptr = B + (size_t)br * N + bn + bc;

  for (int kb = 0; kb < K; kb += 16) {
    const float4 a4 = *(const float4*)(Aptr + kb);
    const float4 b4 = *(const float4*)(Bptr + (size_t)kb * N);
    __syncthreads();
    As[ac + 0][am] = a4.x; As[ac + 1][am] = a4.y;
    As[ac + 2][am] = a4.z; As[ac + 3][am] = a4.w;
    *(float4*)&Bs[br][bc] = b4;
    __syncthreads();
#pragma unroll
    for (int kk = 0; kk < 16; ++kk) {
      const float4 av = *(const float4*)&As[kk][ty << 2];
      const float4 bv = *(const float4*)&Bs[kk][tx << 2];
      acc[0][0] += av.x * bv.x; acc[0][1] += av.x * bv.y; acc[0][2] += av.x * bv.z; acc[0][3] += av.x * bv.w;
      acc[1][0] += av.y * bv.x; acc[1][1] += av.y * bv.y; acc[1][2] += av.y * bv.z; acc[1][3] += av.y * bv.w;
      acc[2][0] += av.z * bv.x; acc[2][1] += av.z * bv.y; acc[2][2] += av.z * bv.z; acc[2][3] += av.z * bv.w;
      acc[3][0] += av.w * bv.x; acc[3][1] += av.w * bv.y; acc[3][2] += av.w * bv.z; acc[3][3] += av.w * bv.w;
    }
  }

  const int cn = bn + (tx << 2);
  const float4 bi = *(const float4*)(bias + cn);
#pragma unroll
  for (int i = 0; i < 4; ++i) {
    const int m = bm + (ty << 2) + i;
    float4 o;
    o.x = acc[i][0] + bi.x; o.y = acc[i][1] + bi.y;
    o.z = acc[i][2] + bi.z; o.w = acc[i][3] + bi.w;
    if (EPI == 0) {
      o.x = 0.5f * o.x * (1.f + erff(o.x * 0.70710678118654752f));
      o.y = 0.5f * o.y * (1.f + erff(o.y * 0.70710678118654752f));
      o.z = 0.5f * o.z * (1.f + erff(o.z * 0.70710678118654752f));
      o.w = 0.5f * o.w * (1.f + erff(o.w * 0.70710678118654752f));
    } else {
      const float4 rv = *(const float4*)(res + (size_t)m * N + cn);
      o.x += rv.x; o.y += rv.y; o.z += rv.z; o.w += rv.w;
    }
    *(float4*)(C + (size_t)m * N + cn) = o;
  }
}

extern "C" void kernel_launch(void* const* d_in, const int* in_sizes, int n_in,
                              void* d_out, int out_size, void* d_ws, size_t ws_size,
                              hipStream_t stream) {
  const float* x      = (const float*)d_in[0];
  const int*   adj    = (const int*)d_in[1];
  const float* stoich = (const float*)d_in[2];
  const float* ln1g   = (const float*)d_in[3];
  const float* ln1b   = (const float*)d_in[4];
  const float* ln2g   = (const float*)d_in[5];
  const float* ln2b   = (const float*)d_in[6];
  const float* W1     = (const float*)d_in[7];
  const float* b1     = (const float*)d_in[8];
  const float* W2     = (const float*)d_in[9];
  const float* b2     = (const float*)d_in[10];
  const float* gW     = (const float*)d_in[11];
  const float* gb     = (const float*)d_in[12];
  float* out = (float*)d_out;
  float* ws  = (float*)d_ws;

  float* normed  = ws;                 // 4M floats (16 MB)
  float* normed2 = ws + 4194304;       // 4M floats (16 MB)
  float* hidden  = ws + 8388608;       // 16M floats (64 MB)

  const int ROWS = BATCH * NTOK;  // 4096

  ln_kernel<<<ROWS, 256, 0, stream>>>(x, ln1g, ln1b, normed);
  attn_kernel<<<ROWS, 256, 0, stream>>>(x, normed, adj, stoich, gW, gb,
                                        ln2g, ln2b, out, normed2);
  // hidden = gelu(normed2 @ W1 + b1)   [4096 x 4096], K=1024
  gemm64<0><<<dim3(64, 64), 256, 0, stream>>>(normed2, W1, b1, nullptr, hidden,
                                              ROWS, 4096, 1024);
  // out = out(x2) + hidden @ W2 + b2   [4096 x 1024], K=4096
  gemm64<1><<<dim3(16, 64), 256, 0, stream>>>(hidden, W2, b2, out, out,
                                              ROWS, 1024, 4096);
}

// Round 2
// 384.697 us; speedup vs baseline: 3.1764x; 3.1764x over previous
//
#include <hip/hip_runtime.h>
#include <math.h>

#define NTOK 1024
#define DMODEL 1024
#define NHEAD 8
#define HDIM 128
#define BATCH 4

typedef __bf16 bf16x8 __attribute__((ext_vector_type(8)));
typedef float  f32x4  __attribute__((ext_vector_type(4)));
typedef unsigned short ushort_t;

static __device__ __forceinline__ ushort_t f2bf(float f) {
  unsigned u = __float_as_uint(f);
  u += 0x7fffu + ((u >> 16) & 1u);   // RNE (inputs are finite)
  return (ushort_t)(u >> 16);
}

static __device__ __forceinline__ void gld16(void* lds, const void* g) {
  __builtin_amdgcn_global_load_lds(
      (const __attribute__((address_space(1))) void*)g,
      (__attribute__((address_space(3))) void*)lds, 16, 0, 0);
}

// ---------------- LayerNorm (x -> normed, fp32) ----------------
__global__ __launch_bounds__(256) void ln_kernel(
    const float* __restrict__ x, const float* __restrict__ g,
    const float* __restrict__ b, float* __restrict__ out)
{
  const int row = blockIdx.x;
  const int tid = threadIdx.x;
  const float* xr = x + (size_t)row * DMODEL;
  float4 v = *(const float4*)(xr + 4 * tid);
  float s1 = v.x + v.y + v.z + v.w;
  float s2 = v.x * v.x + v.y * v.y + v.z * v.z + v.w * v.w;
#pragma unroll
  for (int d = 1; d < 64; d <<= 1) { s1 += __shfl_xor(s1, d); s2 += __shfl_xor(s2, d); }
  __shared__ float red[10];
  const int wid = tid >> 6;
  if ((tid & 63) == 0) { red[wid] = s1; red[4 + wid] = s2; }
  __syncthreads();
  if (tid == 0) {
    float a = red[0] + red[1] + red[2] + red[3];
    float c = red[4] + red[5] + red[6] + red[7];
    float mu = a / (float)DMODEL;
    float var = c / (float)DMODEL - mu * mu;
    red[8] = mu; red[9] = rsqrtf(var + 1e-5f);
  }
  __syncthreads();
  const float mu = red[8], inv = red[9];
  float4 gg = *(const float4*)(g + 4 * tid);
  float4 bb = *(const float4*)(b + 4 * tid);
  float4 o;
  o.x = (v.x - mu) * inv * gg.x + bb.x;
  o.y = (v.y - mu) * inv * gg.y + bb.y;
  o.z = (v.z - mu) * inv * gg.z + bb.z;
  o.w = (v.w - mu) * inv * gg.w + bb.w;
  *(float4*)(out + (size_t)row * DMODEL + 4 * tid) = o;
}

// ---------------- Sparse gated attention + residual + LN2 (bf16 out) --------
__global__ __launch_bounds__(256) void attn_kernel(
    const float* __restrict__ x, const float* __restrict__ normed,
    const int* __restrict__ adj, const float* __restrict__ stoich,
    const float* __restrict__ gW, const float* __restrict__ gb,
    const float* __restrict__ ln2g, const float* __restrict__ ln2b,
    float* __restrict__ xout, ushort_t* __restrict__ normed2)
{
  __shared__ int   neigh[NTOK];
  __shared__ float gateS[NTOK];
  __shared__ float sc[NTOK * NHEAD];  // 32 KB
  __shared__ int   cntS;
  __shared__ float red[10];

  const int bq = blockIdx.x;
  const int b = bq >> 10, q = bq & 1023;
  const int tid = threadIdx.x;

  if (tid == 0) cntS = 0;
  __syncthreads();
  const int* arow = adj + ((size_t)b * NTOK + q) * NTOK;
  for (int k = tid; k < NTOK; k += 256)
    if (arow[k] > 0) { int p = atomicAdd(&cntS, 1); neigh[p] = k; }
  __syncthreads();
  const int cnt = cntS;

  const float st = stoich[b * NTOK + q];
  for (int i = tid; i < cnt; i += 256) {
    int k = neigh[i];
    float z = fmaf(st, gW[k], gb[k]);
    gateS[i] = 1.f / (1.f + expf(-z));
  }
  __syncthreads();

  const float* nb = normed + (size_t)b * NTOK * DMODEL;
  const float4 qv = *(const float4*)(nb + (size_t)q * DMODEL + 4 * tid);
  const int head = tid >> 5, lane = tid & 31;
  const float scale = 0.08838834764831845f;  // 1/sqrt(128)

  for (int i = 0; i < cnt; ++i) {
    const float4 kv = *(const float4*)(nb + (size_t)neigh[i] * DMODEL + 4 * tid);
    float p = qv.x * kv.x + qv.y * kv.y + qv.z * kv.z + qv.w * kv.w;
    p += __shfl_xor(p, 1);  p += __shfl_xor(p, 2);  p += __shfl_xor(p, 4);
    p += __shfl_xor(p, 8);  p += __shfl_xor(p, 16);
    if (lane == 0) sc[i * NHEAD + head] = p * scale * gateS[i];
  }
  __syncthreads();

  float m = -1e30f;
  for (int i = lane; i < cnt; i += 32) m = fmaxf(m, sc[i * NHEAD + head]);
#pragma unroll
  for (int d = 1; d < 32; d <<= 1) m = fmaxf(m, __shfl_xor(m, d));
  float ssum = 0.f;
  for (int i = lane; i < cnt; i += 32) {
    float e = expf(sc[i * NHEAD + head] - m);
    sc[i * NHEAD + head] = e;
    ssum += e;
  }
#pragma unroll
  for (int d = 1; d < 32; d <<= 1) ssum += __shfl_xor(ssum, d);
  const float pinv = 1.f / ssum;
  __syncthreads();

  float4 o = make_float4(0.f, 0.f, 0.f, 0.f);
  for (int i = 0; i < cnt; ++i) {
    const float p = sc[i * NHEAD + head];
    const float4 kv = *(const float4*)(nb + (size_t)neigh[i] * DMODEL + 4 * tid);
    o.x = fmaf(p, kv.x, o.x); o.y = fmaf(p, kv.y, o.y);
    o.z = fmaf(p, kv.z, o.z); o.w = fmaf(p, kv.w, o.w);
  }

  const float4 xv = *(const float4*)(x + ((size_t)b * NTOK + q) * DMODEL + 4 * tid);
  float4 r;
  r.x = xv.x + o.x * pinv; r.y = xv.y + o.y * pinv;
  r.z = xv.z + o.z * pinv; r.w = xv.w + o.w * pinv;
  *(float4*)(xout + ((size_t)b * NTOK + q) * DMODEL + 4 * tid) = r;

  float s1 = r.x + r.y + r.z + r.w;
  float s2 = r.x * r.x + r.y * r.y + r.z * r.z + r.w * r.w;
#pragma unroll
  for (int d = 1; d < 64; d <<= 1) { s1 += __shfl_xor(s1, d); s2 += __shfl_xor(s2, d); }
  const int wid = tid >> 6;
  if ((tid & 63) == 0) { red[wid] = s1; red[4 + wid] = s2; }
  __syncthreads();
  if (tid == 0) {
    float a = red[0] + red[1] + red[2] + red[3];
    float c = red[4] + red[5] + red[6] + red[7];
    float mu = a / (float)DMODEL;
    float var = c / (float)DMODEL - mu * mu;
    red[8] = mu; red[9] = rsqrtf(var + 1e-5f);
  }
  __syncthreads();
  const float mu = red[8], inv = red[9];
  float4 gg = *(const float4*)(ln2g + 4 * tid);
  float4 bb = *(const float4*)(ln2b + 4 * tid);
  ushort4 pk;
  pk.x = f2bf((r.x - mu) * inv * gg.x + bb.x);
  pk.y = f2bf((r.y - mu) * inv * gg.y + bb.y);
  pk.z = f2bf((r.z - mu) * inv * gg.z + bb.z);
  pk.w = f2bf((r.w - mu) * inv * gg.w + bb.w);
  *(ushort4*)(normed2 + ((size_t)b * NTOK + q) * DMODEL + 4 * tid) = pk;
}

// --------- transpose-convert: W fp32 [K][N] -> Wt bf16 [N][K] ---------------
__global__ __launch_bounds__(256) void transpose_bf16(
    const float* __restrict__ W, ushort_t* __restrict__ Wt, int K, int N)
{
  __shared__ float t[32][33];
  const int kb = blockIdx.y * 32, nb = blockIdx.x * 32;
  const int c = threadIdx.x & 31, r0 = threadIdx.x >> 5;  // 8 row-groups
#pragma unroll
  for (int r = r0; r < 32; r += 8)
    t[r][c] = W[(size_t)(kb + r) * N + nb + c];
  __syncthreads();
#pragma unroll
  for (int r = r0; r < 32; r += 8)
    Wt[(size_t)(nb + r) * K + kb + c] = f2bf(t[c][r]);
}

// ---------------- bf16 MFMA GEMM: C[M][N] = A[M][K] @ Bt[N][K]^T ------------
// 128x128 tile, 4 waves (2x2), each wave 64x64 = 4x4 MFMA 16x16x32 tiles.
// EPI==0: C(bf16) = gelu(acc + bias)
// EPI==1: C(f32)  = res + acc + bias
template <int EPI>
__global__ __launch_bounds__(256) void gemm_mfma(
    const ushort_t* __restrict__ A, const ushort_t* __restrict__ Bt,
    const float* __restrict__ bias, const float* __restrict__ res,
    void* __restrict__ Cout, int M, int N, int K)
{
  __shared__ __align__(16) ushort_t As[128 * 32];  // 8 KB
  __shared__ __align__(16) ushort_t Bs[128 * 32];  // 8 KB

  const int tid = threadIdx.x;
  const int w = tid >> 6, l = tid & 63;
  const int bm = blockIdx.y * 128, bn = blockIdx.x * 128;
  const int wm = (w >> 1) * 64, wn = (w & 1) * 64;

  // staging: thread t loads rows t/4 and t/4+64, k-bytes (t&3)*16
  const int srow = tid >> 2;
  const int kelem = (tid & 3) * 8;
  const ushort_t* Ag0 = A + (size_t)(bm + srow) * K + kelem;
  const ushort_t* Ag1 = A + (size_t)(bm + srow + 64) * K + kelem;
  const ushort_t* Bg0 = Bt + (size_t)(bn + srow) * K + kelem;
  const ushort_t* Bg1 = Bt + (size_t)(bn + srow + 64) * K + kelem;
  ushort_t* AsW0 = As + w * 512;         // wave-uniform LDS bases
  ushort_t* AsW1 = As + w * 512 + 2048;
  ushort_t* BsW0 = Bs + w * 512;
  ushort_t* BsW1 = Bs + w * 512 + 2048;

  const int quad = l >> 4, lrow = l & 15;
  const ushort_t* aRd = As + (wm + lrow) * 32 + quad * 8;
  const ushort_t* bRd = Bs + (wn + lrow) * 32 + quad * 8;

  f32x4 acc[4][4] = {};

  for (int kb = 0; kb < K; kb += 32) {
    __syncthreads();
    gld16(AsW0, Ag0 + kb);
    gld16(AsW1, Ag1 + kb);
    gld16(BsW0, Bg0 + kb);
    gld16(BsW1, Bg1 + kb);
    __syncthreads();
    bf16x8 af[4], bfr[4];
#pragma unroll
    for (int i = 0; i < 4; ++i) af[i] = *(const bf16x8*)(aRd + i * 16 * 32);
#pragma unroll
    for (int j = 0; j < 4; ++j) bfr[j] = *(const bf16x8*)(bRd + j * 16 * 32);
#pragma unroll
    for (int i = 0; i < 4; ++i)
#pragma unroll
      for (int j = 0; j < 4; ++j)
        acc[i][j] = __builtin_amdgcn_mfma_f32_16x16x32_bf16(af[i], bfr[j], acc[i][j], 0, 0, 0);
  }

  // epilogue: lane l, reg r -> C[bm+wm+16i+quad*4+r][bn+wn+16j+lrow]
#pragma unroll
  for (int i = 0; i < 4; ++i) {
    const int row0 = bm + wm + 16 * i + quad * 4;
#pragma unroll
    for (int j = 0; j < 4; ++j) {
      const int col = bn + wn + 16 * j + lrow;
      const float bi = bias[col];
#pragma unroll
      for (int r = 0; r < 4; ++r) {
        const int row = row0 + r;
        float v = acc[i][j][r] + bi;
        if (EPI == 0) {
          v = 0.5f * v * (1.f + erff(v * 0.70710678118654752f));
          ((ushort_t*)Cout)[(size_t)row * N + col] = f2bf(v);
        } else {
          v += res[(size_t)row * N + col];
          ((float*)Cout)[(size_t)row * N + col] = v;
        }
      }
    }
  }
}

extern "C" void kernel_launch(void* const* d_in, const int* in_sizes, int n_in,
                              void* d_out, int out_size, void* d_ws, size_t ws_size,
                              hipStream_t stream) {
  const float* x      = (const float*)d_in[0];
  const int*   adj    = (const int*)d_in[1];
  const float* stoich = (const float*)d_in[2];
  const float* ln1g   = (const float*)d_in[3];
  const float* ln1b   = (const float*)d_in[4];
  const float* ln2g   = (const float*)d_in[5];
  const float* ln2b   = (const float*)d_in[6];
  const float* W1     = (const float*)d_in[7];
  const float* b1     = (const float*)d_in[8];
  const float* W2     = (const float*)d_in[9];
  const float* b2     = (const float*)d_in[10];
  const float* gW     = (const float*)d_in[11];
  const float* gb     = (const float*)d_in[12];
  float* out = (float*)d_out;
  char* ws = (char*)d_ws;

  float*    normed  = (float*)(ws);                         // 16 MB
  ushort_t* normed2 = (ushort_t*)(ws + (16u << 20));        //  8 MB
  ushort_t* hidden  = (ushort_t*)(ws + (24u << 20));        // 32 MB
  ushort_t* W1t     = (ushort_t*)(ws + (56u << 20));        //  8 MB
  ushort_t* W2t     = (ushort_t*)(ws + (64u << 20));        //  8 MB

  const int ROWS = BATCH * NTOK;  // 4096

  // weight transposes (independent of activations)
  transpose_bf16<<<dim3(4096 / 32, 1024 / 32), 256, 0, stream>>>(W1, W1t, 1024, 4096);
  transpose_bf16<<<dim3(1024 / 32, 4096 / 32), 256, 0, stream>>>(W2, W2t, 4096, 1024);

  ln_kernel<<<ROWS, 256, 0, stream>>>(x, ln1g, ln1b, normed);
  attn_kernel<<<ROWS, 256, 0, stream>>>(x, normed, adj, stoich, gW, gb,
                                        ln2g, ln2b, out, normed2);
  // hidden(bf16) = gelu(normed2 @ W1 + b1): M=4096 N=4096 K=1024
  gemm_mfma<0><<<dim3(32, 32), 256, 0, stream>>>(normed2, W1t, b1, nullptr,
                                                 hidden, ROWS, 4096, 1024);
  // out(f32) = out + hidden @ W2 + b2: M=4096 N=1024 K=4096
  gemm_mfma<1><<<dim3(8, 32), 256, 0, stream>>>(hidden, W2t, b2, out,
                                                out, ROWS, 1024, 4096);
}

// Round 4
// 323.002 us; speedup vs baseline: 3.7831x; 1.1910x over previous
//
#include <hip/hip_runtime.h>
#include <math.h>

#define NTOK 1024
#define DMODEL 1024
#define NHEAD 8
#define HDIM 128
#define BATCH 4

typedef __bf16 bf16x8 __attribute__((ext_vector_type(8)));
typedef float  f32x4  __attribute__((ext_vector_type(4)));
typedef unsigned short ushort_t;

static __device__ __forceinline__ ushort_t f2bf(float f) {
  unsigned u = __float_as_uint(f);
  u += 0x7fffu + ((u >> 16) & 1u);   // RNE (inputs are finite)
  return (ushort_t)(u >> 16);
}

static __device__ __forceinline__ void gld16(void* lds, const void* g) {
  __builtin_amdgcn_global_load_lds(
      (const __attribute__((address_space(1))) void*)g,
      (__attribute__((address_space(3))) void*)lds, 16, 0, 0);
}

// ---------------- LayerNorm (x -> normed, fp32) ----------------
__global__ __launch_bounds__(256) void ln_kernel(
    const float* __restrict__ x, const float* __restrict__ g,
    const float* __restrict__ b, float* __restrict__ out)
{
  const int row = blockIdx.x;
  const int tid = threadIdx.x;
  const float* xr = x + (size_t)row * DMODEL;
  float4 v = *(const float4*)(xr + 4 * tid);
  float s1 = v.x + v.y + v.z + v.w;
  float s2 = v.x * v.x + v.y * v.y + v.z * v.z + v.w * v.w;
#pragma unroll
  for (int d = 1; d < 64; d <<= 1) { s1 += __shfl_xor(s1, d); s2 += __shfl_xor(s2, d); }
  __shared__ float red[10];
  const int wid = tid >> 6;
  if ((tid & 63) == 0) { red[wid] = s1; red[4 + wid] = s2; }
  __syncthreads();
  if (tid == 0) {
    float a = red[0] + red[1] + red[2] + red[3];
    float c = red[4] + red[5] + red[6] + red[7];
    float mu = a / (float)DMODEL;
    float var = c / (float)DMODEL - mu * mu;
    red[8] = mu; red[9] = rsqrtf(var + 1e-5f);
  }
  __syncthreads();
  const float mu = red[8], inv = red[9];
  float4 gg = *(const float4*)(g + 4 * tid);
  float4 bb = *(const float4*)(b + 4 * tid);
  float4 o;
  o.x = (v.x - mu) * inv * gg.x + bb.x;
  o.y = (v.y - mu) * inv * gg.y + bb.y;
  o.z = (v.z - mu) * inv * gg.z + bb.z;
  o.w = (v.w - mu) * inv * gg.w + bb.w;
  *(float4*)(out + (size_t)row * DMODEL + 4 * tid) = o;
}

// ---- Sparse gated attention (online softmax) + residual + LN2 (bf16 out) ---
// one block per (b,q); 256 threads; thread t owns dims [4t,4t+4)
// writes x2 (residual, fp32) to workspace; d_out is written ONLY by gemm2.
__global__ __launch_bounds__(256) void attn_kernel(
    const float* __restrict__ x, const float* __restrict__ normed,
    const int* __restrict__ adj, const float* __restrict__ stoich,
    const float* __restrict__ gW, const float* __restrict__ gb,
    const float* __restrict__ ln2g, const float* __restrict__ ln2b,
    float* __restrict__ x2out, ushort_t* __restrict__ normed2)
{
  __shared__ int   neigh[NTOK];
  __shared__ float gateS[NTOK];
  __shared__ int   cntS;
  __shared__ float red[10];

  const int bq = blockIdx.x;
  const int b = bq >> 10, q = bq & 1023;
  const int tid = threadIdx.x;

  if (tid == 0) cntS = 0;
  __syncthreads();
  const int* arow = adj + ((size_t)b * NTOK + q) * NTOK;
  {
    const int4 a4 = ((const int4*)arow)[tid];
    const int k0 = 4 * tid;
    if (a4.x > 0) { int p = atomicAdd(&cntS, 1); neigh[p] = k0; }
    if (a4.y > 0) { int p = atomicAdd(&cntS, 1); neigh[p] = k0 + 1; }
    if (a4.z > 0) { int p = atomicAdd(&cntS, 1); neigh[p] = k0 + 2; }
    if (a4.w > 0) { int p = atomicAdd(&cntS, 1); neigh[p] = k0 + 3; }
  }
  __syncthreads();
  const int cnt = cntS;

  const float st = stoich[b * NTOK + q];
  for (int i = tid; i < cnt; i += 256) {
    int k = neigh[i];
    float z = fmaf(st, gW[k], gb[k]);
    gateS[i] = 1.f / (1.f + __expf(-z));
  }
  __syncthreads();

  const float* nb = normed + (size_t)b * NTOK * DMODEL;
  const float4 qv = *(const float4*)(nb + (size_t)q * DMODEL + 4 * tid);
  const float scale = 0.08838834764831845f;  // 1/sqrt(128)

  float m = -1e30f, lsum = 0.f;
  float4 o = make_float4(0.f, 0.f, 0.f, 0.f);

  for (int i0 = 0; i0 < cnt; i0 += 4) {
    float4 kv[4]; float gt[4];
#pragma unroll
    for (int u = 0; u < 4; ++u) {
      const int i = i0 + u;
      const int idx = neigh[(i < cnt) ? i : 0];
      kv[u] = *(const float4*)(nb + (size_t)idx * DMODEL + 4 * tid);
      gt[u] = gateS[(i < cnt) ? i : 0];
    }
#pragma unroll
    for (int u = 0; u < 4; ++u) {
      const int i = i0 + u;
      float p = kv[u].x * qv.x + kv[u].y * qv.y + kv[u].z * qv.z + kv[u].w * qv.w;
      p += __shfl_xor(p, 1);  p += __shfl_xor(p, 2);  p += __shfl_xor(p, 4);
      p += __shfl_xor(p, 8);  p += __shfl_xor(p, 16);
      const float s = (i < cnt) ? p * scale * gt[u] : -1e30f;
      const float mn = fmaxf(m, s);
      const float alpha = __expf(m - mn);
      const float wv = __expf(s - mn);
      lsum = lsum * alpha + wv;
      o.x = o.x * alpha + wv * kv[u].x;
      o.y = o.y * alpha + wv * kv[u].y;
      o.z = o.z * alpha + wv * kv[u].z;
      o.w = o.w * alpha + wv * kv[u].w;
      m = mn;
    }
  }
  const float pinv = 1.f / lsum;

  const float4 xv = *(const float4*)(x + ((size_t)b * NTOK + q) * DMODEL + 4 * tid);
  float4 r;
  r.x = xv.x + o.x * pinv; r.y = xv.y + o.y * pinv;
  r.z = xv.z + o.z * pinv; r.w = xv.w + o.w * pinv;
  *(float4*)(x2out + ((size_t)b * NTOK + q) * DMODEL + 4 * tid) = r;

  // fused LN2
  float s1 = r.x + r.y + r.z + r.w;
  float s2 = r.x * r.x + r.y * r.y + r.z * r.z + r.w * r.w;
#pragma unroll
  for (int d = 1; d < 64; d <<= 1) { s1 += __shfl_xor(s1, d); s2 += __shfl_xor(s2, d); }
  const int wid = tid >> 6;
  if ((tid & 63) == 0) { red[wid] = s1; red[4 + wid] = s2; }
  __syncthreads();
  if (tid == 0) {
    float a = red[0] + red[1] + red[2] + red[3];
    float c = red[4] + red[5] + red[6] + red[7];
    float mu = a / (float)DMODEL;
    float var = c / (float)DMODEL - mu * mu;
    red[8] = mu; red[9] = rsqrtf(var + 1e-5f);
  }
  __syncthreads();
  const float mu = red[8], inv = red[9];
  float4 gg = *(const float4*)(ln2g + 4 * tid);
  float4 bb = *(const float4*)(ln2b + 4 * tid);
  ushort4 pk;
  pk.x = f2bf((r.x - mu) * inv * gg.x + bb.x);
  pk.y = f2bf((r.y - mu) * inv * gg.y + bb.y);
  pk.z = f2bf((r.z - mu) * inv * gg.z + bb.z);
  pk.w = f2bf((r.w - mu) * inv * gg.w + bb.w);
  *(ushort4*)(normed2 + ((size_t)b * NTOK + q) * DMODEL + 4 * tid) = pk;
}

// --------- transpose-convert: W fp32 [K][N] -> Wt bf16 [N][K] ---------------
__global__ __launch_bounds__(256) void transpose_bf16(
    const float* __restrict__ W, ushort_t* __restrict__ Wt, int K, int N)
{
  __shared__ float t[32][33];
  const int kb = blockIdx.y * 32, nb = blockIdx.x * 32;
  const int c = threadIdx.x & 31, r0 = threadIdx.x >> 5;
#pragma unroll
  for (int r = r0; r < 32; r += 8)
    t[r][c] = W[(size_t)(kb + r) * N + nb + c];
  __syncthreads();
#pragma unroll
  for (int r = r0; r < 32; r += 8)
    Wt[(size_t)(nb + r) * K + kb + c] = f2bf(t[c][r]);
}

// ---------------- bf16 MFMA GEMM: C[M][N] = A[M][K] @ Bt[N][K]^T ------------
// 128x128 tile, 4 waves (2x2), each wave 64x64 = 4x4 MFMA 16x16x32 tiles.
// EPI==0: C(bf16) = gelu(acc + bias);  EPI==1: C(f32) = res + acc + bias
template <int EPI>
__global__ __launch_bounds__(256) void gemm_mfma(
    const ushort_t* __restrict__ A, const ushort_t* __restrict__ Bt,
    const float* __restrict__ bias, const float* __restrict__ res,
    void* __restrict__ Cout, int M, int N, int K)
{
  __shared__ __align__(16) ushort_t As[128 * 32];
  __shared__ __align__(16) ushort_t Bs[128 * 32];

  const int tid = threadIdx.x;
  const int w = tid >> 6, l = tid & 63;
  const int bm = blockIdx.y * 128, bn = blockIdx.x * 128;
  const int wm = (w >> 1) * 64, wn = (w & 1) * 64;

  const int srow = tid >> 2;
  const int kelem = (tid & 3) * 8;
  const ushort_t* Ag0 = A + (size_t)(bm + srow) * K + kelem;
  const ushort_t* Ag1 = A + (size_t)(bm + srow + 64) * K + kelem;
  const ushort_t* Bg0 = Bt + (size_t)(bn + srow) * K + kelem;
  const ushort_t* Bg1 = Bt + (size_t)(bn + srow + 64) * K + kelem;
  ushort_t* AsW0 = As + w * 512;
  ushort_t* AsW1 = As + w * 512 + 2048;
  ushort_t* BsW0 = Bs + w * 512;
  ushort_t* BsW1 = Bs + w * 512 + 2048;

  const int quad = l >> 4, lrow = l & 15;
  const ushort_t* aRd = As + (wm + lrow) * 32 + quad * 8;
  const ushort_t* bRd = Bs + (wn + lrow) * 32 + quad * 8;

  f32x4 acc[4][4] = {};

  for (int kb = 0; kb < K; kb += 32) {
    __syncthreads();
    gld16(AsW0, Ag0 + kb);
    gld16(AsW1, Ag1 + kb);
    gld16(BsW0, Bg0 + kb);
    gld16(BsW1, Bg1 + kb);
    __syncthreads();
    bf16x8 af[4], bfr[4];
#pragma unroll
    for (int i = 0; i < 4; ++i) af[i] = *(const bf16x8*)(aRd + i * 16 * 32);
#pragma unroll
    for (int j = 0; j < 4; ++j) bfr[j] = *(const bf16x8*)(bRd + j * 16 * 32);
#pragma unroll
    for (int i = 0; i < 4; ++i)
#pragma unroll
      for (int j = 0; j < 4; ++j)
        acc[i][j] = __builtin_amdgcn_mfma_f32_16x16x32_bf16(af[i], bfr[j], acc[i][j], 0, 0, 0);
  }

#pragma unroll
  for (int i = 0; i < 4; ++i) {
    const int row0 = bm + wm + 16 * i + quad * 4;
#pragma unroll
    for (int j = 0; j < 4; ++j) {
      const int col = bn + wn + 16 * j + lrow;
      const float bi = bias[col];
#pragma unroll
      for (int r = 0; r < 4; ++r) {
        const int row = row0 + r;
        float v = acc[i][j][r] + bi;
        if (EPI == 0) {
          v = 0.5f * v * (1.f + erff(v * 0.70710678118654752f));
          ((ushort_t*)Cout)[(size_t)row * N + col] = f2bf(v);
        } else {
          v += res[(size_t)row * N + col];
          ((float*)Cout)[(size_t)row * N + col] = v;
        }
      }
    }
  }
}

extern "C" void kernel_launch(void* const* d_in, const int* in_sizes, int n_in,
                              void* d_out, int out_size, void* d_ws, size_t ws_size,
                              hipStream_t stream) {
  const float* x      = (const float*)d_in[0];
  const int*   adj    = (const int*)d_in[1];
  const float* stoich = (const float*)d_in[2];
  const float* ln1g   = (const float*)d_in[3];
  const float* ln1b   = (const float*)d_in[4];
  const float* ln2g   = (const float*)d_in[5];
  const float* ln2b   = (const float*)d_in[6];
  const float* W1     = (const float*)d_in[7];
  const float* b1     = (const float*)d_in[8];
  const float* W2     = (const float*)d_in[9];
  const float* b2     = (const float*)d_in[10];
  const float* gW     = (const float*)d_in[11];
  const float* gb     = (const float*)d_in[12];
  float* out = (float*)d_out;
  char* ws = (char*)d_ws;

  float*    normed  = (float*)(ws);                         // 16 MB
  ushort_t* normed2 = (ushort_t*)(ws + (16u << 20));        //  8 MB
  ushort_t* hidden  = (ushort_t*)(ws + (24u << 20));        // 32 MB
  ushort_t* W1t     = (ushort_t*)(ws + (56u << 20));        //  8 MB
  ushort_t* W2t     = (ushort_t*)(ws + (64u << 20));        //  8 MB
  float*    x2buf   = (float*)(ws + (72u << 20));           // 16 MB

  const int ROWS = BATCH * NTOK;  // 4096

  transpose_bf16<<<dim3(4096 / 32, 1024 / 32), 256, 0, stream>>>(W1, W1t, 1024, 4096);
  transpose_bf16<<<dim3(1024 / 32, 4096 / 32), 256, 0, stream>>>(W2, W2t, 4096, 1024);

  ln_kernel<<<ROWS, 256, 0, stream>>>(x, ln1g, ln1b, normed);
  attn_kernel<<<ROWS, 256, 0, stream>>>(x, normed, adj, stoich, gW, gb,
                                        ln2g, ln2b, x2buf, normed2);
  // hidden(bf16) = gelu(normed2 @ W1 + b1): M=4096 N=4096 K=1024
  gemm_mfma<0><<<dim3(32, 32), 256, 0, stream>>>(normed2, W1t, b1, nullptr,
                                                 hidden, ROWS, 4096, 1024);
  // out(f32) = x2 + hidden @ W2 + b2: M=4096 N=1024 K=4096 (d_out write-once)
  gemm_mfma<1><<<dim3(8, 32), 256, 0, stream>>>(hidden, W2t, b2, x2buf,
                                                out, ROWS, 1024, 4096);
}

// Round 5
// 314.460 us; speedup vs baseline: 3.8859x; 1.0272x over previous
//
#include <hip/hip_runtime.h>
#include <math.h>

#define NTOK 1024
#define DMODEL 1024
#define NHEAD 8
#define HDIM 128
#define BATCH 4

typedef __bf16 bf16x8 __attribute__((ext_vector_type(8)));
typedef float  f32x4  __attribute__((ext_vector_type(4)));
typedef unsigned short ushort_t;

static __device__ __forceinline__ ushort_t f2bf(float f) {
  unsigned u = __float_as_uint(f);
  u += 0x7fffu + ((u >> 16) & 1u);   // RNE (inputs are finite)
  return (ushort_t)(u >> 16);
}

static __device__ __forceinline__ void gld16(void* lds, const void* g) {
  __builtin_amdgcn_global_load_lds(
      (const __attribute__((address_space(1))) void*)g,
      (__attribute__((address_space(3))) void*)lds, 16, 0, 0);
}

// ---------------- LayerNorm (x -> normed, fp32) ----------------
__global__ __launch_bounds__(256) void ln_kernel(
    const float* __restrict__ x, const float* __restrict__ g,
    const float* __restrict__ b, float* __restrict__ out)
{
  const int row = blockIdx.x;
  const int tid = threadIdx.x;
  const float* xr = x + (size_t)row * DMODEL;
  float4 v = *(const float4*)(xr + 4 * tid);
  float s1 = v.x + v.y + v.z + v.w;
  float s2 = v.x * v.x + v.y * v.y + v.z * v.z + v.w * v.w;
#pragma unroll
  for (int d = 1; d < 64; d <<= 1) { s1 += __shfl_xor(s1, d); s2 += __shfl_xor(s2, d); }
  __shared__ float red[10];
  const int wid = tid >> 6;
  if ((tid & 63) == 0) { red[wid] = s1; red[4 + wid] = s2; }
  __syncthreads();
  if (tid == 0) {
    float a = red[0] + red[1] + red[2] + red[3];
    float c = red[4] + red[5] + red[6] + red[7];
    float mu = a / (float)DMODEL;
    float var = c / (float)DMODEL - mu * mu;
    red[8] = mu; red[9] = rsqrtf(var + 1e-5f);
  }
  __syncthreads();
  const float mu = red[8], inv = red[9];
  float4 gg = *(const float4*)(g + 4 * tid);
  float4 bb = *(const float4*)(b + 4 * tid);
  float4 o;
  o.x = (v.x - mu) * inv * gg.x + bb.x;
  o.y = (v.y - mu) * inv * gg.y + bb.y;
  o.z = (v.z - mu) * inv * gg.z + bb.z;
  o.w = (v.w - mu) * inv * gg.w + bb.w;
  *(float4*)(out + (size_t)row * DMODEL + 4 * tid) = o;
}

// ---- Sparse gated attention (online softmax) + residual + LN2 (bf16 out) ---
// one block per (b,q); 256 threads; thread t owns dims [4t,4t+4)
// Writes (x2 + b2) to d_out; gemm2 split-K blocks atomicAdd on top of it.
__global__ __launch_bounds__(256) void attn_kernel(
    const float* __restrict__ x, const float* __restrict__ normed,
    const int* __restrict__ adj, const float* __restrict__ stoich,
    const float* __restrict__ gW, const float* __restrict__ gb,
    const float* __restrict__ ln2g, const float* __restrict__ ln2b,
    const float* __restrict__ b2,
    float* __restrict__ outbase, ushort_t* __restrict__ normed2)
{
  __shared__ int   neigh[NTOK];
  __shared__ float gateS[NTOK];
  __shared__ int   cntS;
  __shared__ float red[10];

  const int bq = blockIdx.x;
  const int b = bq >> 10, q = bq & 1023;
  const int tid = threadIdx.x;

  if (tid == 0) cntS = 0;
  __syncthreads();
  const int* arow = adj + ((size_t)b * NTOK + q) * NTOK;
  {
    const int4 a4 = ((const int4*)arow)[tid];
    const int k0 = 4 * tid;
    if (a4.x > 0) { int p = atomicAdd(&cntS, 1); neigh[p] = k0; }
    if (a4.y > 0) { int p = atomicAdd(&cntS, 1); neigh[p] = k0 + 1; }
    if (a4.z > 0) { int p = atomicAdd(&cntS, 1); neigh[p] = k0 + 2; }
    if (a4.w > 0) { int p = atomicAdd(&cntS, 1); neigh[p] = k0 + 3; }
  }
  __syncthreads();
  const int cnt = cntS;

  const float st = stoich[b * NTOK + q];
  for (int i = tid; i < cnt; i += 256) {
    int k = neigh[i];
    float z = fmaf(st, gW[k], gb[k]);
    gateS[i] = 1.f / (1.f + __expf(-z));
  }
  __syncthreads();

  const float* nb = normed + (size_t)b * NTOK * DMODEL;
  const float4 qv = *(const float4*)(nb + (size_t)q * DMODEL + 4 * tid);
  const float scale = 0.08838834764831845f;  // 1/sqrt(128)

  float m = -1e30f, lsum = 0.f;
  float4 o = make_float4(0.f, 0.f, 0.f, 0.f);

  for (int i0 = 0; i0 < cnt; i0 += 4) {
    float4 kv[4]; float gt[4];
#pragma unroll
    for (int u = 0; u < 4; ++u) {
      const int i = i0 + u;
      const int idx = neigh[(i < cnt) ? i : 0];
      kv[u] = *(const float4*)(nb + (size_t)idx * DMODEL + 4 * tid);
      gt[u] = gateS[(i < cnt) ? i : 0];
    }
#pragma unroll
    for (int u = 0; u < 4; ++u) {
      const int i = i0 + u;
      float p = kv[u].x * qv.x + kv[u].y * qv.y + kv[u].z * qv.z + kv[u].w * qv.w;
      p += __shfl_xor(p, 1);  p += __shfl_xor(p, 2);  p += __shfl_xor(p, 4);
      p += __shfl_xor(p, 8);  p += __shfl_xor(p, 16);
      const float s = (i < cnt) ? p * scale * gt[u] : -1e30f;
      const float mn = fmaxf(m, s);
      const float alpha = __expf(m - mn);
      const float wv = __expf(s - mn);
      lsum = lsum * alpha + wv;
      o.x = o.x * alpha + wv * kv[u].x;
      o.y = o.y * alpha + wv * kv[u].y;
      o.z = o.z * alpha + wv * kv[u].z;
      o.w = o.w * alpha + wv * kv[u].w;
      m = mn;
    }
  }
  const float pinv = 1.f / lsum;

  const float4 xv = *(const float4*)(x + ((size_t)b * NTOK + q) * DMODEL + 4 * tid);
  float4 r;
  r.x = xv.x + o.x * pinv; r.y = xv.y + o.y * pinv;
  r.z = xv.z + o.z * pinv; r.w = xv.w + o.w * pinv;

  // out base = x2 + b2 (gemm2 atomically accumulates hidden@W2 on top)
  const float4 b2v = *(const float4*)(b2 + 4 * tid);
  float4 ob;
  ob.x = r.x + b2v.x; ob.y = r.y + b2v.y;
  ob.z = r.z + b2v.z; ob.w = r.w + b2v.w;
  *(float4*)(outbase + ((size_t)b * NTOK + q) * DMODEL + 4 * tid) = ob;

  // fused LN2 (on r, without b2)
  float s1 = r.x + r.y + r.z + r.w;
  float s2 = r.x * r.x + r.y * r.y + r.z * r.z + r.w * r.w;
#pragma unroll
  for (int d = 1; d < 64; d <<= 1) { s1 += __shfl_xor(s1, d); s2 += __shfl_xor(s2, d); }
  const int wid = tid >> 6;
  if ((tid & 63) == 0) { red[wid] = s1; red[4 + wid] = s2; }
  __syncthreads();
  if (tid == 0) {
    float a = red[0] + red[1] + red[2] + red[3];
    float c = red[4] + red[5] + red[6] + red[7];
    float mu = a / (float)DMODEL;
    float var = c / (float)DMODEL - mu * mu;
    red[8] = mu; red[9] = rsqrtf(var + 1e-5f);
  }
  __syncthreads();
  const float mu = red[8], inv = red[9];
  float4 gg = *(const float4*)(ln2g + 4 * tid);
  float4 bb = *(const float4*)(ln2b + 4 * tid);
  ushort4 pk;
  pk.x = f2bf((r.x - mu) * inv * gg.x + bb.x);
  pk.y = f2bf((r.y - mu) * inv * gg.y + bb.y);
  pk.z = f2bf((r.z - mu) * inv * gg.z + bb.z);
  pk.w = f2bf((r.w - mu) * inv * gg.w + bb.w);
  *(ushort4*)(normed2 + ((size_t)b * NTOK + q) * DMODEL + 4 * tid) = pk;
}

// --------- transpose-convert: W fp32 [K][N] -> Wt bf16 [N][K] ---------------
__global__ __launch_bounds__(256) void transpose_bf16(
    const float* __restrict__ W, ushort_t* __restrict__ Wt, int K, int N)
{
  __shared__ float t[32][33];
  const int kb = blockIdx.y * 32, nb = blockIdx.x * 32;
  const int c = threadIdx.x & 31, r0 = threadIdx.x >> 5;
#pragma unroll
  for (int r = r0; r < 32; r += 8)
    t[r][c] = W[(size_t)(kb + r) * N + nb + c];
  __syncthreads();
#pragma unroll
  for (int r = r0; r < 32; r += 8)
    Wt[(size_t)(nb + r) * K + kb + c] = f2bf(t[c][r]);
}

// ---------------- bf16 MFMA GEMM1: C[M][N] = gelu(A @ Bt^T + bias), bf16 out
// 128x128 tile, 4 waves (2x2), each wave 64x64 = 4x4 MFMA 16x16x32 tiles.
__global__ __launch_bounds__(256) void gemm_mfma_gelu(
    const ushort_t* __restrict__ A, const ushort_t* __restrict__ Bt,
    const float* __restrict__ bias, ushort_t* __restrict__ Cout,
    int M, int N, int K)
{
  __shared__ __align__(16) ushort_t As[128 * 32];
  __shared__ __align__(16) ushort_t Bs[128 * 32];

  const int tid = threadIdx.x;
  const int w = tid >> 6, l = tid & 63;
  const int bm = blockIdx.y * 128, bn = blockIdx.x * 128;
  const int wm = (w >> 1) * 64, wn = (w & 1) * 64;

  const int srow = tid >> 2;
  const int kelem = (tid & 3) * 8;
  const ushort_t* Ag0 = A + (size_t)(bm + srow) * K + kelem;
  const ushort_t* Ag1 = A + (size_t)(bm + srow + 64) * K + kelem;
  const ushort_t* Bg0 = Bt + (size_t)(bn + srow) * K + kelem;
  const ushort_t* Bg1 = Bt + (size_t)(bn + srow + 64) * K + kelem;
  ushort_t* AsW0 = As + w * 512;
  ushort_t* AsW1 = As + w * 512 + 2048;
  ushort_t* BsW0 = Bs + w * 512;
  ushort_t* BsW1 = Bs + w * 512 + 2048;

  const int quad = l >> 4, lrow = l & 15;
  const ushort_t* aRd = As + (wm + lrow) * 32 + quad * 8;
  const ushort_t* bRd = Bs + (wn + lrow) * 32 + quad * 8;

  f32x4 acc[4][4] = {};

  for (int kb = 0; kb < K; kb += 32) {
    __syncthreads();
    gld16(AsW0, Ag0 + kb);
    gld16(AsW1, Ag1 + kb);
    gld16(BsW0, Bg0 + kb);
    gld16(BsW1, Bg1 + kb);
    __syncthreads();
    bf16x8 af[4], bfr[4];
#pragma unroll
    for (int i = 0; i < 4; ++i) af[i] = *(const bf16x8*)(aRd + i * 16 * 32);
#pragma unroll
    for (int j = 0; j < 4; ++j) bfr[j] = *(const bf16x8*)(bRd + j * 16 * 32);
#pragma unroll
    for (int i = 0; i < 4; ++i)
#pragma unroll
      for (int j = 0; j < 4; ++j)
        acc[i][j] = __builtin_amdgcn_mfma_f32_16x16x32_bf16(af[i], bfr[j], acc[i][j], 0, 0, 0);
  }

#pragma unroll
  for (int i = 0; i < 4; ++i) {
    const int row0 = bm + wm + 16 * i + quad * 4;
#pragma unroll
    for (int j = 0; j < 4; ++j) {
      const int col = bn + wn + 16 * j + lrow;
      const float bi = bias[col];
#pragma unroll
      for (int r = 0; r < 4; ++r) {
        const int row = row0 + r;
        float v = acc[i][j][r] + bi;
        v = 0.5f * v * (1.f + erff(v * 0.70710678118654752f));
        Cout[(size_t)row * N + col] = f2bf(v);
      }
    }
  }
}

// ---------------- bf16 MFMA GEMM2 (split-K): Cout += A @ Bt^T ---------------
// grid (N/128, M/128, KS); block z handles K-chunk [z*kchunk, (z+1)*kchunk).
// fp32 atomicAdd epilogue into Cout (pre-initialized with x2 + b2 by attn).
__global__ __launch_bounds__(256) void gemm_mfma_splitk(
    const ushort_t* __restrict__ A, const ushort_t* __restrict__ Bt,
    float* __restrict__ Cout, int M, int N, int K, int kchunk)
{
  __shared__ __align__(16) ushort_t As[128 * 32];
  __shared__ __align__(16) ushort_t Bs[128 * 32];

  const int tid = threadIdx.x;
  const int w = tid >> 6, l = tid & 63;
  const int bm = blockIdx.y * 128, bn = blockIdx.x * 128;
  const int wm = (w >> 1) * 64, wn = (w & 1) * 64;
  const int koff = blockIdx.z * kchunk;

  const int srow = tid >> 2;
  const int kelem = (tid & 3) * 8;
  const ushort_t* Ag0 = A + (size_t)(bm + srow) * K + koff + kelem;
  const ushort_t* Ag1 = A + (size_t)(bm + srow + 64) * K + koff + kelem;
  const ushort_t* Bg0 = Bt + (size_t)(bn + srow) * K + koff + kelem;
  const ushort_t* Bg1 = Bt + (size_t)(bn + srow + 64) * K + koff + kelem;
  ushort_t* AsW0 = As + w * 512;
  ushort_t* AsW1 = As + w * 512 + 2048;
  ushort_t* BsW0 = Bs + w * 512;
  ushort_t* BsW1 = Bs + w * 512 + 2048;

  const int quad = l >> 4, lrow = l & 15;
  const ushort_t* aRd = As + (wm + lrow) * 32 + quad * 8;
  const ushort_t* bRd = Bs + (wn + lrow) * 32 + quad * 8;

  f32x4 acc[4][4] = {};

  for (int kb = 0; kb < kchunk; kb += 32) {
    __syncthreads();
    gld16(AsW0, Ag0 + kb);
    gld16(AsW1, Ag1 + kb);
    gld16(BsW0, Bg0 + kb);
    gld16(BsW1, Bg1 + kb);
    __syncthreads();
    bf16x8 af[4], bfr[4];
#pragma unroll
    for (int i = 0; i < 4; ++i) af[i] = *(const bf16x8*)(aRd + i * 16 * 32);
#pragma unroll
    for (int j = 0; j < 4; ++j) bfr[j] = *(const bf16x8*)(bRd + j * 16 * 32);
#pragma unroll
    for (int i = 0; i < 4; ++i)
#pragma unroll
      for (int j = 0; j < 4; ++j)
        acc[i][j] = __builtin_amdgcn_mfma_f32_16x16x32_bf16(af[i], bfr[j], acc[i][j], 0, 0, 0);
  }

#pragma unroll
  for (int i = 0; i < 4; ++i) {
    const int row0 = bm + wm + 16 * i + quad * 4;
#pragma unroll
    for (int j = 0; j < 4; ++j) {
      const int col = bn + wn + 16 * j + lrow;
#pragma unroll
      for (int r = 0; r < 4; ++r) {
        const int row = row0 + r;
        atomicAdd(&Cout[(size_t)row * N + col], acc[i][j][r]);
      }
    }
  }
}

extern "C" void kernel_launch(void* const* d_in, const int* in_sizes, int n_in,
                              void* d_out, int out_size, void* d_ws, size_t ws_size,
                              hipStream_t stream) {
  const float* x      = (const float*)d_in[0];
  const int*   adj    = (const int*)d_in[1];
  const float* stoich = (const float*)d_in[2];
  const float* ln1g   = (const float*)d_in[3];
  const float* ln1b   = (const float*)d_in[4];
  const float* ln2g   = (const float*)d_in[5];
  const float* ln2b   = (const float*)d_in[6];
  const float* W1     = (const float*)d_in[7];
  const float* b1     = (const float*)d_in[8];
  const float* W2     = (const float*)d_in[9];
  const float* b2     = (const float*)d_in[10];
  const float* gW     = (const float*)d_in[11];
  const float* gb     = (const float*)d_in[12];
  float* out = (float*)d_out;
  char* ws = (char*)d_ws;

  float*    normed  = (float*)(ws);                         // 16 MB
  ushort_t* normed2 = (ushort_t*)(ws + (16u << 20));        //  8 MB
  ushort_t* hidden  = (ushort_t*)(ws + (24u << 20));        // 32 MB
  ushort_t* W1t     = (ushort_t*)(ws + (56u << 20));        //  8 MB
  ushort_t* W2t     = (ushort_t*)(ws + (64u << 20));        //  8 MB

  const int ROWS = BATCH * NTOK;  // 4096

  transpose_bf16<<<dim3(4096 / 32, 1024 / 32), 256, 0, stream>>>(W1, W1t, 1024, 4096);
  transpose_bf16<<<dim3(1024 / 32, 4096 / 32), 256, 0, stream>>>(W2, W2t, 4096, 1024);

  ln_kernel<<<ROWS, 256, 0, stream>>>(x, ln1g, ln1b, normed);
  attn_kernel<<<ROWS, 256, 0, stream>>>(x, normed, adj, stoich, gW, gb,
                                        ln2g, ln2b, b2, out, normed2);
  // hidden(bf16) = gelu(normed2 @ W1 + b1): M=4096 N=4096 K=1024
  gemm_mfma_gelu<<<dim3(32, 32), 256, 0, stream>>>(normed2, W1t, b1, hidden,
                                                   ROWS, 4096, 1024);
  // out += hidden @ W2 (split-K=2, atomic fp32): M=4096 N=1024 K=4096
  gemm_mfma_splitk<<<dim3(8, 32, 2), 256, 0, stream>>>(hidden, W2t, out,
                                                       ROWS, 1024, 4096, 2048);
}